// Round 13
// baseline (560.263 us; speedup 1.0000x reference)
//
#include <hip/hip_runtime.h>

#define NN 100000
#define NE 1600000
#define NG 64
#define BN_EPS 1e-5f

#define TOT (2 * NN)

// bucketed CSR build: 392 buckets of 512 keys (key >> 9), keys < 200000
#define NB 392
#define KPB 512
#define BDEPTH 32                 // per-bucket LDS staging depth (phase 1)
#define BCAP 10240                // padded per-bucket capacity (avg 8163)
#define P1B 512                   // phase-1 blocks
#define EPB ((NE + P1B - 1) / P1B)

// fused-stats partials
#define GG 1563                   // gemm grid = (NN+63)/64
#define PB 1600                   // padded partial row length

// k_init grid layout
#define CVTB 6250                 // cvt blocks (NN*16/256)
#define WTB 61                    // weight-swizzle blocks
#define INITB (CVTB + WTB + 1)

typedef __attribute__((ext_vector_type(8))) _Float16 f16x8;
typedef __attribute__((ext_vector_type(8))) unsigned short u16x8;
typedef __attribute__((ext_vector_type(4))) float f32x4;

__device__ __forceinline__ float h2f(unsigned short u) {
  _Float16 h; __builtin_memcpy(&h, &u, 2); return (float)h;
}
__device__ __forceinline__ unsigned short f2h(float f) {
  _Float16 h = (_Float16)f; unsigned short u; __builtin_memcpy(&u, &h, 2); return u;
}

__device__ __forceinline__ int lower_bound_dev(const int* a, int n, int key) {
  int lo = 0, hi = n;
  while (lo < hi) { int mid = (lo + hi) >> 1; if (a[mid] < key) lo = mid + 1; else hi = mid; }
  return lo;
}

// ---------------------------------------------------------------- init: x->fp16, weight swizzle, ssid, zero gcur/pool
struct WtArgs { const float* W[9]; };
__global__ __launch_bounds__(256) void k_init(const float* __restrict__ x,
    unsigned short* __restrict__ xb, WtArgs a, unsigned short* __restrict__ wt,
    float* __restrict__ ssid, int* __restrict__ gcur, float* __restrict__ pool) {
  int bid = blockIdx.x;
  int tid = threadIdx.x;
  if (bid < CVTB) {
    size_t i = (size_t)bid * 256 + tid;   // float4 index, CVTB*256 == NN*16 exactly
    float4 v = *(const float4*)(x + i * 4);
    ushort4 o;
    o.x = f2h(v.x); o.y = f2h(v.y); o.z = f2h(v.z); o.w = f2h(v.w);
    *(ushort4*)(xb + i * 4) = o;
    return;
  }
  if (bid < CVTB + WTB) {
    int t = (bid - CVTB) * 256 + tid;
    if (t >= 15360) {
      int u = t - 15360;
      if (u < 128) { ssid[u] = 1.f; ssid[128 + u] = 0.f; }
      return;
    }
    int p, rem, KS;
    if (t < 3072) { p = t >> 10; rem = t & 1023; KS = 2; }
    else { int u = t - 3072; p = 3 + (u >> 11); rem = u & 2047; KS = 4; }
    int ks = rem >> 9;
    int rem2 = rem & 511;
    int nt = rem2 >> 6;
    int lane = rem2 & 63;
    int L = p / 3, op = p - L * 3;
    int lbase = (L == 0) ? 0 : (24576 + (L - 1) * 49152);
    size_t dst = (size_t)lbase + (size_t)op * KS * 4096 + (size_t)(ks * 8 + nt) * 512 + lane * 8;
    const float* W = a.W[p];
    int krow = ks * 32 + (lane >> 4) * 8;
    int col = nt * 16 + (lane & 15);
    #pragma unroll
    for (int j = 0; j < 8; ++j)
      wt[dst + j] = f2h(W[(size_t)(krow + j) * 128 + col]);
    return;
  }
  // last block: zero gcur + pool
  for (int i = tid; i < NB; i += 256) gcur[i] = 0;
  for (int i = tid; i < NG * 128; i += 256) pool[i] = 0.f;
}

// ---------------------------------------------------------------- CSR phase 1: bucket scatter, periodic flush
// pair stream: edge (s,d) -> (key=d, pay=s) and (key=s+NN, pay=d). val = (key&511)<<17 | pay
__global__ __launch_bounds__(512) void k_p1(const int* __restrict__ src,
    const int* __restrict__ dst, int* __restrict__ gcur, unsigned int* __restrict__ pairs) {
  __shared__ unsigned int lbuf[NB][BDEPTH];   // 50 KB
  __shared__ int lcnt[NB], lbase[NB];
  __shared__ int sc[512];
  int t = threadIdx.x;
  for (int i = t; i < NB; i += 512) lcnt[i] = 0;
  __syncthreads();
  int e0 = blockIdx.x * EPB;
  int e1 = min(e0 + EPB, NE);
  int niter = (e1 - e0 + 511) >> 9;
  for (int it = 0; it < niter; ++it) {
    int e = e0 + (it << 9) + t;
    if (e < e1) {
      int s = src[e], d = dst[e];
      {
        int key = d;
        unsigned int val = ((unsigned int)(key & (KPB - 1)) << 17) | (unsigned int)s;
        int bk = key >> 9;
        int p = atomicAdd(&lcnt[bk], 1);
        if (p < BDEPTH) lbuf[bk][p] = val;
        else { int g = atomicAdd(&gcur[bk], 1); pairs[(size_t)bk * BCAP + g] = val; }
      }
      {
        int key = s + NN;
        unsigned int val = ((unsigned int)(key & (KPB - 1)) << 17) | (unsigned int)d;
        int bk = key >> 9;
        int p = atomicAdd(&lcnt[bk], 1);
        if (p < BDEPTH) lbuf[bk][p] = val;
        else { int g = atomicAdd(&gcur[bk], 1); pairs[(size_t)bk * BCAP + g] = val; }
      }
    }
    // flush staged pairs every 2 iterations (~2048 pairs, ~5.2/bucket) and at the end
    if ((it & 1) || (it == niter - 1)) {
      __syncthreads();
      if (t < NB) {
        int c = min(lcnt[t], BDEPTH);
        lcnt[t] = c;
        lbase[t] = atomicAdd(&gcur[t], c);
      }
      __syncthreads();
      sc[t] = (t < NB) ? lcnt[t] : 0;
      __syncthreads();
      for (int off = 1; off < 512; off <<= 1) {
        int v = (t >= off) ? sc[t - off] : 0;
        __syncthreads();
        sc[t] += v;
        __syncthreads();
      }
      int total = sc[NB - 1];
      for (int idx = t; idx < total; idx += 512) {
        int lo = 0, hi = NB - 1;
        while (lo < hi) { int mid = (lo + hi) >> 1; if (sc[mid] > idx) hi = mid; else lo = mid + 1; }
        int within = idx - ((lo == 0) ? 0 : sc[lo - 1]);
        pairs[(size_t)lo * BCAP + lbase[lo] + within] = lbuf[lo][within];
      }
      __syncthreads();
      for (int i = t; i < NB; i += 512) lcnt[i] = 0;
      __syncthreads();
    }
  }
}

// ---------------------------------------------------------------- CSR phase 2: per-bucket hist/scan/scatter (self-computed base)
__global__ __launch_bounds__(256) void k_p2(const unsigned int* __restrict__ pairs,
    const int* __restrict__ gcur, int* __restrict__ offs, int* __restrict__ nbr) {
  int b = blockIdx.x;
  int n = gcur[b];
  __shared__ int hist[KPB];
  __shared__ int sc[256];
  int t = threadIdx.x;
  // base = sum gcur[0..b)
  int partial = 0;
  for (int i = t; i < b; i += 256) partial += gcur[i];
  sc[t] = partial;
  __syncthreads();
  for (int off = 128; off > 0; off >>= 1) {
    if (t < off) sc[t] += sc[t + off];
    __syncthreads();
  }
  int base = sc[0];
  __syncthreads();
  #pragma unroll
  for (int j = 0; j < 2; ++j) hist[t * 2 + j] = 0;
  __syncthreads();
  const unsigned int* bp = pairs + (size_t)b * BCAP;
  for (int i = t; i < n; i += 256) atomicAdd(&hist[bp[i] >> 17], 1);
  __syncthreads();
  int v[2]; int tsum = 0;
  #pragma unroll
  for (int j = 0; j < 2; ++j) { v[j] = hist[t * 2 + j]; tsum += v[j]; }
  sc[t] = tsum;
  __syncthreads();
  for (int off = 1; off < 256; off <<= 1) {
    int x = (t >= off) ? sc[t - off] : 0;
    __syncthreads();
    sc[t] += x;
    __syncthreads();
  }
  int run = (t == 0) ? 0 : sc[t - 1];
  #pragma unroll
  for (int j = 0; j < 2; ++j) {
    int key = b * KPB + t * 2 + j;
    if (key < TOT) offs[key] = base + run;
    hist[t * 2 + j] = run;
    run += v[j];
  }
  if (b == NB - 1 && t == 0) offs[TOT] = base + n;
  __syncthreads();
  for (int i = t; i < n; i += 256) {
    unsigned int u = bp[i];
    int lk = (int)(u >> 17);
    int pos = atomicAdd(&hist[lk], 1);
    nbr[base + pos] = (int)(u & 0x1FFFFu);
  }
}

// ---------------------------------------------------------------- gather (fp16 in, fp16 out, end-affine BN, NT agg store)
template<int DIN>
__global__ __launch_bounds__(256) void k_gather(const unsigned short* __restrict__ xb,
    const float* __restrict__ ss, const int* __restrict__ offs, const int* __restrict__ nbr,
    unsigned short* __restrict__ aggi, unsigned short* __restrict__ aggo) {
  constexpr int GW = DIN / 8;
  constexpr int GPB = 256 / GW;
  int g = blockIdx.x * GPB + threadIdx.x / GW;
  if (g >= TOT) return;
  int c0 = (threadIdx.x % GW) * 8;
  int beg = offs[g], end = offs[g + 1];
  f16x8 acc;
  #pragma unroll
  for (int j = 0; j < 8; ++j) acc[j] = (_Float16)0.f;
  int k = beg;
  for (; k + 8 <= end; k += 8) {
    int n0 = nbr[k],     n1 = nbr[k + 1], n2 = nbr[k + 2], n3 = nbr[k + 3];
    int n4 = nbr[k + 4], n5 = nbr[k + 5], n6 = nbr[k + 6], n7 = nbr[k + 7];
    f16x8 v0 = *(const f16x8*)(xb + (size_t)n0 * DIN + c0);
    f16x8 v1 = *(const f16x8*)(xb + (size_t)n1 * DIN + c0);
    f16x8 v2 = *(const f16x8*)(xb + (size_t)n2 * DIN + c0);
    f16x8 v3 = *(const f16x8*)(xb + (size_t)n3 * DIN + c0);
    f16x8 v4 = *(const f16x8*)(xb + (size_t)n4 * DIN + c0);
    f16x8 v5 = *(const f16x8*)(xb + (size_t)n5 * DIN + c0);
    f16x8 v6 = *(const f16x8*)(xb + (size_t)n6 * DIN + c0);
    f16x8 v7 = *(const f16x8*)(xb + (size_t)n7 * DIN + c0);
    acc += ((v0 + v1) + (v2 + v3)) + ((v4 + v5) + (v6 + v7));
  }
  for (; k < end; ++k) {
    f16x8 v = *(const f16x8*)(xb + (size_t)nbr[k] * DIN + c0);
    acc += v;
  }
  float cnt = (float)(end - beg);
  union { u16x8 v; unsigned short u[8]; } r;
  #pragma unroll
  for (int j = 0; j < 8; ++j)
    r.u[j] = f2h(fmaf((float)acc[j], ss[c0 + j], cnt * ss[128 + c0 + j]));
  unsigned short* o = (g < NN) ? (aggi + (size_t)g * DIN) : (aggo + (size_t)(g - NN) * DIN);
  __builtin_nontemporal_store(r.v, (u16x8*)(o + c0));
}

// ---------------------------------------------------------------- MFMA GEMM: relu(BN(A0)@W0 + A1@W1 + A2@W2) -> fp16, fused BN stats
template<int KD>
__global__ __launch_bounds__(256) void k_gemm(const unsigned short* __restrict__ A0,
    const float* __restrict__ ss, const unsigned short* __restrict__ A1,
    const unsigned short* __restrict__ A2, const unsigned short* __restrict__ wt,
    unsigned short* __restrict__ out, float* __restrict__ part) {
  constexpr int KS = KD / 32;
  int tid = threadIdx.x;
  int lane = tid & 63;
  int w = tid >> 6;
  int m0 = blockIdx.x * 64 + w * 16;
  int arow = m0 + (lane & 15);
  int koff = (lane >> 4) * 8;
  f32x4 acc[8];
  #pragma unroll
  for (int nt = 0; nt < 8; ++nt) acc[nt] = (f32x4){0.f, 0.f, 0.f, 0.f};

  const unsigned short* As[3] = {A0, A1, A2};
  #pragma unroll
  for (int op = 0; op < 3; ++op) {
    const unsigned short* __restrict__ A = As[op];
    f16x8 af[KS];
    if (arow < NN) {
      #pragma unroll
      for (int ks = 0; ks < KS; ++ks)
        af[ks] = *(const f16x8*)(A + (size_t)arow * KD + ks * 32 + koff);
      if (op == 0) {
        #pragma unroll
        for (int ks = 0; ks < KS; ++ks) {
          #pragma unroll
          for (int j = 0; j < 8; ++j) {
            int c = ks * 32 + koff + j;
            af[ks][j] = (_Float16)fmaf((float)af[ks][j], ss[c], ss[128 + c]);
          }
        }
      }
    } else {
      #pragma unroll
      for (int ks = 0; ks < KS; ++ks)
        #pragma unroll
        for (int j = 0; j < 8; ++j) af[ks][j] = (_Float16)0.f;
    }
    #pragma unroll
    for (int ks = 0; ks < KS; ++ks) {
      #pragma unroll
      for (int nt = 0; nt < 8; ++nt) {
        f16x8 bf = *(const f16x8*)(wt + ((size_t)(op * KS + ks) * 8 + nt) * 512 + lane * 8);
        acc[nt] = __builtin_amdgcn_mfma_f32_16x16x32_f16(af[ks], bf, acc[nt], 0, 0, 0);
      }
    }
  }

  // epilogue: relu -> fp16, LDS repack + per-thread stats
  __shared__ unsigned short lds[4][16][128];
  __shared__ float sws[4][128], sws2[4][128];
  float s8[8], s28[8];
  #pragma unroll
  for (int nt = 0; nt < 8; ++nt) { s8[nt] = 0.f; s28[nt] = 0.f; }
  #pragma unroll
  for (int nt = 0; nt < 8; ++nt)
    #pragma unroll
    for (int r = 0; r < 4; ++r) {
      float v = fmaxf(acc[nt][r], 0.f);
      lds[w][(lane >> 4) * 4 + r][nt * 16 + (lane & 15)] = f2h(v);
      s8[nt] += v;
      s28[nt] = fmaf(v, v, s28[nt]);
    }
  #pragma unroll
  for (int it = 0; it < 4; ++it) {
    int rr = (lane >> 4) + it * 4;
    int cc = (lane & 15) * 8;
    int grow = m0 + rr;
    if (grow < NN)
      *(u16x8*)(out + (size_t)grow * 128 + cc) = *(const u16x8*)&lds[w][rr][cc];
  }
  // wave-reduce stats across the 4 row-groups (lanes ^16, ^32)
  #pragma unroll
  for (int nt = 0; nt < 8; ++nt) {
    s8[nt]  += __shfl_xor(s8[nt], 16);
    s8[nt]  += __shfl_xor(s8[nt], 32);
    s28[nt] += __shfl_xor(s28[nt], 16);
    s28[nt] += __shfl_xor(s28[nt], 32);
  }
  if (lane < 16) {
    #pragma unroll
    for (int nt = 0; nt < 8; ++nt) {
      sws[w][nt * 16 + lane]  = s8[nt];
      sws2[w][nt * 16 + lane] = s28[nt];
    }
  }
  __syncthreads();
  if (tid < 128) {
    float S  = sws[0][tid] + sws[1][tid] + sws[2][tid] + sws[3][tid];
    float S2 = sws2[0][tid] + sws2[1][tid] + sws2[2][tid] + sws2[3][tid];
    part[(size_t)tid * PB + blockIdx.x]         = S;
    part[(size_t)(128 + tid) * PB + blockIdx.x] = S2;
  }
}

// ---------------------------------------------------------------- fold per-block partials -> scale/shift
__global__ __launch_bounds__(256) void k_bn_final(const float* __restrict__ part,
    const float* __restrict__ g, const float* __restrict__ b, float* __restrict__ ss) {
  int c = blockIdx.x;   // 128 channels
  int t = threadIdx.x;  // 256
  float s = 0.f, s2 = 0.f;
  for (int i = t; i < GG; i += 256) {
    s  += part[(size_t)c * PB + i];
    s2 += part[(size_t)(128 + c) * PB + i];
  }
  __shared__ float rs[256], rs2[256];
  rs[t] = s; rs2[t] = s2; __syncthreads();
  for (int off = 128; off > 0; off >>= 1) {
    if (t < off) { rs[t] += rs[t + off]; rs2[t] += rs2[t + off]; }
    __syncthreads();
  }
  if (t == 0) {
    float mu = rs[0] / (float)NN;
    float var = rs2[0] / (float)NN - mu * mu;
    float rcp = rsqrtf(var + BN_EPS);
    float sc = rcp * g[c];
    ss[c] = sc;
    ss[128 + c] = b[c] - mu * sc;
  }
}

// ---------------------------------------------------------------- graph mean-pool (raw fp16 sums)
__global__ __launch_bounds__(128) void k_pool(const unsigned short* __restrict__ hb,
    const int* __restrict__ batch, float* __restrict__ pool) {
  int c = threadIdx.x;
  int n0 = blockIdx.x * 256;
  if (n0 >= NN) return;
  int nend = n0 + 256; if (nend > NN) nend = NN;
  int cur = batch[n0];
  float run = 0.f;
  for (int n = n0; n < nend; ++n) {
    int g = batch[n];
    if (g != cur) { atomicAdd(&pool[(size_t)cur * 128 + c], run); run = 0.f; cur = g; }
    run += h2f(hb[(size_t)n * 128 + c]);
  }
  atomicAdd(&pool[(size_t)cur * 128 + c], run);
}

__global__ __launch_bounds__(128) void k_final(const float* __restrict__ pool,
    const int* __restrict__ batch, const float* __restrict__ ss, float* __restrict__ out) {
  int g = blockIdx.x;
  int c = threadIdx.x;
  __shared__ int cnt;
  if (c == 0) {
    int lo = lower_bound_dev(batch, NN, g);
    int hi = lower_bound_dev(batch, NN, g + 1);
    cnt = hi - lo;
  }
  __syncthreads();
  float d = (float)(cnt > 1 ? cnt : 1);
  out[(size_t)g * 128 + c] = fmaf(pool[(size_t)g * 128 + c] / d, ss[c], ss[128 + c]);
}

// ---------------------------------------------------------------- launch
extern "C" void kernel_launch(void* const* d_in, const int* in_sizes, int n_in,
                              void* d_out, int out_size, void* d_ws, size_t ws_size,
                              hipStream_t stream) {
  const float* x     = (const float*)d_in[0];
  const int*   ei    = (const int*)d_in[1];
  const int*   batch = (const int*)d_in[2];
  const float* gg[3] = {(const float*)d_in[6], (const float*)d_in[11], (const float*)d_in[16]};
  const float* bbv[3]= {(const float*)d_in[7], (const float*)d_in[12], (const float*)d_in[17]};
  const int* src = ei;
  const int* dst = ei + NE;

  uintptr_t p = ((uintptr_t)d_ws + 255) & ~(uintptr_t)255;
  auto alloc = [&](size_t bytes) { uintptr_t r = p; p = (p + bytes + 255) & ~(uintptr_t)255; return r; };

  unsigned int* pairs = (unsigned int*)alloc((size_t)NB * BCAP * 4);
  int* gcur  = (int*)alloc(NB * 4);
  int* offs  = (int*)alloc((TOT + 1) * 4);
  int* nbr   = (int*)alloc((size_t)2 * NE * 4);
  unsigned short* xb   = (unsigned short*)alloc((size_t)NN * 64 * 2);
  unsigned short* hb0  = (unsigned short*)alloc((size_t)NN * 128 * 2);
  unsigned short* hb1  = (unsigned short*)alloc((size_t)NN * 128 * 2);
  unsigned short* hb2  = (unsigned short*)alloc((size_t)NN * 128 * 2);
  unsigned short* aggi = (unsigned short*)alloc((size_t)NN * 128 * 2);
  unsigned short* aggo = (unsigned short*)alloc((size_t)NN * 128 * 2);
  unsigned short* wt   = (unsigned short*)alloc(122880 * 2);
  float* part  = (float*)alloc((size_t)256 * PB * 4);
  float* ss_id = (float*)alloc(256 * 4);
  float* ss0   = (float*)alloc(256 * 4);
  float* ss1   = (float*)alloc(256 * 4);
  float* ss2   = (float*)alloc(256 * 4);
  float* pool  = (float*)alloc((size_t)NG * 128 * 4);

  // init: cvt + weight swizzle + ssid + zero gcur/pool (one dispatch)
  WtArgs wa;
  wa.W[0] = (const float*)d_in[3];  wa.W[1] = (const float*)d_in[4];  wa.W[2] = (const float*)d_in[5];
  wa.W[3] = (const float*)d_in[8];  wa.W[4] = (const float*)d_in[9];  wa.W[5] = (const float*)d_in[10];
  wa.W[6] = (const float*)d_in[13]; wa.W[7] = (const float*)d_in[14]; wa.W[8] = (const float*)d_in[15];
  k_init<<<INITB, 256, 0, stream>>>(x, xb, wa, wt, ss_id, gcur, pool);

  // CSR build (bucketed, write-combined with periodic flush, self-based p2)
  k_p1<<<P1B, 512, 0, stream>>>(src, dst, gcur, pairs);
  k_p2<<<NB, 256, 0, stream>>>(pairs, gcur, offs, nbr);

  // layer 0 (KD=64): xb -> hb0
  k_gather<64><<<(TOT + 31) / 32, 256, 0, stream>>>(xb, ss_id, offs, nbr, aggi, aggo);
  k_gemm<64><<<GG, 256, 0, stream>>>(xb, ss_id, aggi, aggo, wt + 0, hb0, part);
  k_bn_final<<<128, 256, 0, stream>>>(part, gg[0], bbv[0], ss0);

  // layer 1 (KD=128): hb0 -> hb1
  k_gather<128><<<(TOT + 15) / 16, 256, 0, stream>>>(hb0, ss0, offs, nbr, aggi, aggo);
  k_gemm<128><<<GG, 256, 0, stream>>>(hb0, ss0, aggi, aggo, wt + 24576, hb1, part);
  k_bn_final<<<128, 256, 0, stream>>>(part, gg[1], bbv[1], ss1);

  // layer 2 (KD=128): hb1 -> hb2
  k_gather<128><<<(TOT + 15) / 16, 256, 0, stream>>>(hb1, ss1, offs, nbr, aggi, aggo);
  k_gemm<128><<<GG, 256, 0, stream>>>(hb1, ss1, aggi, aggo, wt + 73728, hb2, part);
  k_bn_final<<<128, 256, 0, stream>>>(part, gg[2], bbv[2], ss2);

  // pool
  k_pool<<<(NN + 255) / 256, 128, 0, stream>>>(hb2, batch, pool);
  k_final<<<NG, 128, 0, stream>>>(pool, batch, ss2, (float*)d_out);
}

// Round 15
// 538.236 us; speedup vs baseline: 1.0409x; 1.0409x over previous
//
#include <hip/hip_runtime.h>

#define NN 100000
#define NE 1600000
#define NG 64
#define BN_EPS 1e-5f

#define TOT (2 * NN)

// bucketed CSR build: 392 buckets of 512 keys (key >> 9), keys < 200000
#define NB 392
#define KPB 512
#define BDEPTH 32                 // per-bucket LDS staging depth (phase 1)
#define BCAP 10240                // padded per-bucket capacity (avg 8163)
#define P1B 512                   // phase-1 blocks
#define EPB ((NE + P1B - 1) / P1B)

// fused-stats partials
#define GG 1563                   // gemm grid = (NN+63)/64
#define PB 1600                   // padded partial row length

// k_init grid layout
#define CVTB 6250                 // cvt blocks (NN*16/256)
#define WTB 61                    // weight-swizzle blocks
#define INITB (CVTB + WTB + 1)

typedef __attribute__((ext_vector_type(8))) _Float16 f16x8;
typedef __attribute__((ext_vector_type(8))) unsigned short u16x8;
typedef __attribute__((ext_vector_type(4))) float f32x4;

__device__ __forceinline__ float h2f(unsigned short u) {
  _Float16 h; __builtin_memcpy(&h, &u, 2); return (float)h;
}
__device__ __forceinline__ unsigned short f2h(float f) {
  _Float16 h = (_Float16)f; unsigned short u; __builtin_memcpy(&u, &h, 2); return u;
}

__device__ __forceinline__ int lower_bound_dev(const int* a, int n, int key) {
  int lo = 0, hi = n;
  while (lo < hi) { int mid = (lo + hi) >> 1; if (a[mid] < key) lo = mid + 1; else hi = mid; }
  return lo;
}

// ---------------------------------------------------------------- init: x->fp16, weight swizzle, ssid, zero gcur/pool
struct WtArgs { const float* W[9]; };
__global__ __launch_bounds__(256) void k_init(const float* __restrict__ x,
    unsigned short* __restrict__ xb, WtArgs a, unsigned short* __restrict__ wt,
    float* __restrict__ ssid, int* __restrict__ gcur, float* __restrict__ pool) {
  int bid = blockIdx.x;
  int tid = threadIdx.x;
  if (bid < CVTB) {
    size_t i = (size_t)bid * 256 + tid;   // float4 index, CVTB*256 == NN*16 exactly
    float4 v = *(const float4*)(x + i * 4);
    ushort4 o;
    o.x = f2h(v.x); o.y = f2h(v.y); o.z = f2h(v.z); o.w = f2h(v.w);
    *(ushort4*)(xb + i * 4) = o;
    return;
  }
  if (bid < CVTB + WTB) {
    int t = (bid - CVTB) * 256 + tid;
    if (t >= 15360) {
      int u = t - 15360;
      if (u < 128) { ssid[u] = 1.f; ssid[128 + u] = 0.f; }
      return;
    }
    int p, rem, KS;
    if (t < 3072) { p = t >> 10; rem = t & 1023; KS = 2; }
    else { int u = t - 3072; p = 3 + (u >> 11); rem = u & 2047; KS = 4; }
    int ks = rem >> 9;
    int rem2 = rem & 511;
    int nt = rem2 >> 6;
    int lane = rem2 & 63;
    int L = p / 3, op = p - L * 3;
    int lbase = (L == 0) ? 0 : (24576 + (L - 1) * 49152);
    size_t dst = (size_t)lbase + (size_t)op * KS * 4096 + (size_t)(ks * 8 + nt) * 512 + lane * 8;
    const float* W = a.W[p];
    int krow = ks * 32 + (lane >> 4) * 8;
    int col = nt * 16 + (lane & 15);
    #pragma unroll
    for (int j = 0; j < 8; ++j)
      wt[dst + j] = f2h(W[(size_t)(krow + j) * 128 + col]);
    return;
  }
  // last block: zero gcur + pool
  for (int i = tid; i < NB; i += 256) gcur[i] = 0;
  for (int i = tid; i < NG * 128; i += 256) pool[i] = 0.f;
}

// ---------------------------------------------------------------- CSR phase 1: bucket scatter (write-combined)
// pair stream: edge (s,d) -> (key=d, pay=s) and (key=s+NN, pay=d). val = (key&511)<<17 | pay
__global__ __launch_bounds__(512) void k_p1(const int* __restrict__ src,
    const int* __restrict__ dst, int* __restrict__ gcur, unsigned int* __restrict__ pairs) {
  __shared__ unsigned int lbuf[NB][BDEPTH];   // 50 KB
  __shared__ int lcnt[NB], lbase[NB];
  __shared__ int sc[512];
  int t = threadIdx.x;
  for (int i = t; i < NB; i += 512) lcnt[i] = 0;
  __syncthreads();
  int e0 = blockIdx.x * EPB;
  int e1 = min(e0 + EPB, NE);
  for (int e = e0 + t; e < e1; e += 512) {
    int s = src[e], d = dst[e];
    {
      int key = d;
      unsigned int val = ((unsigned int)(key & (KPB - 1)) << 17) | (unsigned int)s;
      int bk = key >> 9;
      int p = atomicAdd(&lcnt[bk], 1);
      if (p < BDEPTH) lbuf[bk][p] = val;
      else { int g = atomicAdd(&gcur[bk], 1); pairs[(size_t)bk * BCAP + g] = val; }
    }
    {
      int key = s + NN;
      unsigned int val = ((unsigned int)(key & (KPB - 1)) << 17) | (unsigned int)d;
      int bk = key >> 9;
      int p = atomicAdd(&lcnt[bk], 1);
      if (p < BDEPTH) lbuf[bk][p] = val;
      else { int g = atomicAdd(&gcur[bk], 1); pairs[(size_t)bk * BCAP + g] = val; }
    }
  }
  __syncthreads();
  if (t < NB) {
    int c = min(lcnt[t], BDEPTH);
    lcnt[t] = c;
    lbase[t] = atomicAdd(&gcur[t], c);
  }
  __syncthreads();
  sc[t] = (t < NB) ? lcnt[t] : 0;
  __syncthreads();
  for (int off = 1; off < 512; off <<= 1) {
    int x = (t >= off) ? sc[t - off] : 0;
    __syncthreads();
    sc[t] += x;
    __syncthreads();
  }
  int total = sc[NB - 1];
  for (int idx = t; idx < total; idx += 512) {
    int lo = 0, hi = NB - 1;
    while (lo < hi) { int mid = (lo + hi) >> 1; if (sc[mid] > idx) hi = mid; else lo = mid + 1; }
    int within = idx - ((lo == 0) ? 0 : sc[lo - 1]);
    pairs[(size_t)lo * BCAP + lbase[lo] + within] = lbuf[lo][within];
  }
}

// ---------------------------------------------------------------- CSR phase 2: per-bucket hist/scan/scatter (self-computed base)
__global__ __launch_bounds__(256) void k_p2(const unsigned int* __restrict__ pairs,
    const int* __restrict__ gcur, int* __restrict__ offs, int* __restrict__ nbr) {
  int b = blockIdx.x;
  int n = gcur[b];
  __shared__ int hist[KPB];
  __shared__ int sc[256];
  int t = threadIdx.x;
  // base = sum gcur[0..b)
  int partial = 0;
  for (int i = t; i < b; i += 256) partial += gcur[i];
  sc[t] = partial;
  __syncthreads();
  for (int off = 128; off > 0; off >>= 1) {
    if (t < off) sc[t] += sc[t + off];
    __syncthreads();
  }
  int base = sc[0];
  __syncthreads();
  #pragma unroll
  for (int j = 0; j < 2; ++j) hist[t * 2 + j] = 0;
  __syncthreads();
  const unsigned int* bp = pairs + (size_t)b * BCAP;
  for (int i = t; i < n; i += 256) atomicAdd(&hist[bp[i] >> 17], 1);
  __syncthreads();
  int v[2]; int tsum = 0;
  #pragma unroll
  for (int j = 0; j < 2; ++j) { v[j] = hist[t * 2 + j]; tsum += v[j]; }
  sc[t] = tsum;
  __syncthreads();
  for (int off = 1; off < 256; off <<= 1) {
    int x = (t >= off) ? sc[t - off] : 0;
    __syncthreads();
    sc[t] += x;
    __syncthreads();
  }
  int run = (t == 0) ? 0 : sc[t - 1];
  #pragma unroll
  for (int j = 0; j < 2; ++j) {
    int key = b * KPB + t * 2 + j;
    if (key < TOT) offs[key] = base + run;
    hist[t * 2 + j] = run;
    run += v[j];
  }
  if (b == NB - 1 && t == 0) offs[TOT] = base + n;
  __syncthreads();
  for (int i = t; i < n; i += 256) {
    unsigned int u = bp[i];
    int lk = (int)(u >> 17);
    int pos = atomicAdd(&hist[lk], 1);
    nbr[base + pos] = (int)(u & 0x1FFFFu);
  }
}

// ---------------------------------------------------------------- gather (fp16 in, fp16 out, end-affine BN, NT agg store)
template<int DIN>
__global__ __launch_bounds__(256) void k_gather(const unsigned short* __restrict__ xb,
    const float* __restrict__ ss, const int* __restrict__ offs, const int* __restrict__ nbr,
    unsigned short* __restrict__ aggi, unsigned short* __restrict__ aggo) {
  constexpr int GW = DIN / 8;
  constexpr int GPB = 256 / GW;
  int g = blockIdx.x * GPB + threadIdx.x / GW;
  if (g >= TOT) return;
  int c0 = (threadIdx.x % GW) * 8;
  int beg = offs[g], end = offs[g + 1];
  f16x8 acc;
  #pragma unroll
  for (int j = 0; j < 8; ++j) acc[j] = (_Float16)0.f;
  int k = beg;
  for (; k + 8 <= end; k += 8) {
    int n0 = nbr[k],     n1 = nbr[k + 1], n2 = nbr[k + 2], n3 = nbr[k + 3];
    int n4 = nbr[k + 4], n5 = nbr[k + 5], n6 = nbr[k + 6], n7 = nbr[k + 7];
    f16x8 v0 = *(const f16x8*)(xb + (size_t)n0 * DIN + c0);
    f16x8 v1 = *(const f16x8*)(xb + (size_t)n1 * DIN + c0);
    f16x8 v2 = *(const f16x8*)(xb + (size_t)n2 * DIN + c0);
    f16x8 v3 = *(const f16x8*)(xb + (size_t)n3 * DIN + c0);
    f16x8 v4 = *(const f16x8*)(xb + (size_t)n4 * DIN + c0);
    f16x8 v5 = *(const f16x8*)(xb + (size_t)n5 * DIN + c0);
    f16x8 v6 = *(const f16x8*)(xb + (size_t)n6 * DIN + c0);
    f16x8 v7 = *(const f16x8*)(xb + (size_t)n7 * DIN + c0);
    acc += ((v0 + v1) + (v2 + v3)) + ((v4 + v5) + (v6 + v7));
  }
  for (; k < end; ++k) {
    f16x8 v = *(const f16x8*)(xb + (size_t)nbr[k] * DIN + c0);
    acc += v;
  }
  float cnt = (float)(end - beg);
  union { u16x8 v; unsigned short u[8]; } r;
  #pragma unroll
  for (int j = 0; j < 8; ++j)
    r.u[j] = f2h(fmaf((float)acc[j], ss[c0 + j], cnt * ss[128 + c0 + j]));
  unsigned short* o = (g < NN) ? (aggi + (size_t)g * DIN) : (aggo + (size_t)(g - NN) * DIN);
  __builtin_nontemporal_store(r.v, (u16x8*)(o + c0));
}

// ---------------------------------------------------------------- MFMA GEMM: relu(BN(A0)@W0 + A1@W1 + A2@W2) -> fp16, fused BN stats
template<int KD>
__global__ __launch_bounds__(256) void k_gemm(const unsigned short* __restrict__ A0,
    const float* __restrict__ ss, const unsigned short* __restrict__ A1,
    const unsigned short* __restrict__ A2, const unsigned short* __restrict__ wt,
    unsigned short* __restrict__ out, float* __restrict__ part) {
  constexpr int KS = KD / 32;
  int tid = threadIdx.x;
  int lane = tid & 63;
  int w = tid >> 6;
  int m0 = blockIdx.x * 64 + w * 16;
  int arow = m0 + (lane & 15);
  int koff = (lane >> 4) * 8;
  f32x4 acc[8];
  #pragma unroll
  for (int nt = 0; nt < 8; ++nt) acc[nt] = (f32x4){0.f, 0.f, 0.f, 0.f};

  const unsigned short* As[3] = {A0, A1, A2};
  #pragma unroll
  for (int op = 0; op < 3; ++op) {
    const unsigned short* __restrict__ A = As[op];
    f16x8 af[KS];
    if (arow < NN) {
      #pragma unroll
      for (int ks = 0; ks < KS; ++ks)
        af[ks] = *(const f16x8*)(A + (size_t)arow * KD + ks * 32 + koff);
      if (op == 0) {
        #pragma unroll
        for (int ks = 0; ks < KS; ++ks) {
          #pragma unroll
          for (int j = 0; j < 8; ++j) {
            int c = ks * 32 + koff + j;
            af[ks][j] = (_Float16)fmaf((float)af[ks][j], ss[c], ss[128 + c]);
          }
        }
      }
    } else {
      #pragma unroll
      for (int ks = 0; ks < KS; ++ks)
        #pragma unroll
        for (int j = 0; j < 8; ++j) af[ks][j] = (_Float16)0.f;
    }
    #pragma unroll
    for (int ks = 0; ks < KS; ++ks) {
      #pragma unroll
      for (int nt = 0; nt < 8; ++nt) {
        f16x8 bf = *(const f16x8*)(wt + ((size_t)(op * KS + ks) * 8 + nt) * 512 + lane * 8);
        acc[nt] = __builtin_amdgcn_mfma_f32_16x16x32_f16(af[ks], bf, acc[nt], 0, 0, 0);
      }
    }
  }

  // epilogue: relu -> fp16, LDS repack + per-thread stats
  __shared__ unsigned short lds[4][16][128];
  __shared__ float sws[4][128], sws2[4][128];
  float s8[8], s28[8];
  #pragma unroll
  for (int nt = 0; nt < 8; ++nt) { s8[nt] = 0.f; s28[nt] = 0.f; }
  #pragma unroll
  for (int nt = 0; nt < 8; ++nt)
    #pragma unroll
    for (int r = 0; r < 4; ++r) {
      float v = fmaxf(acc[nt][r], 0.f);
      lds[w][(lane >> 4) * 4 + r][nt * 16 + (lane & 15)] = f2h(v);
      s8[nt] += v;
      s28[nt] = fmaf(v, v, s28[nt]);
    }
  #pragma unroll
  for (int it = 0; it < 4; ++it) {
    int rr = (lane >> 4) + it * 4;
    int cc = (lane & 15) * 8;
    int grow = m0 + rr;
    if (grow < NN)
      *(u16x8*)(out + (size_t)grow * 128 + cc) = *(const u16x8*)&lds[w][rr][cc];
  }
  // wave-reduce stats across the 4 row-groups (lanes ^16, ^32)
  #pragma unroll
  for (int nt = 0; nt < 8; ++nt) {
    s8[nt]  += __shfl_xor(s8[nt], 16);
    s8[nt]  += __shfl_xor(s8[nt], 32);
    s28[nt] += __shfl_xor(s28[nt], 16);
    s28[nt] += __shfl_xor(s28[nt], 32);
  }
  if (lane < 16) {
    #pragma unroll
    for (int nt = 0; nt < 8; ++nt) {
      sws[w][nt * 16 + lane]  = s8[nt];
      sws2[w][nt * 16 + lane] = s28[nt];
    }
  }
  __syncthreads();
  if (tid < 128) {
    float S  = sws[0][tid] + sws[1][tid] + sws[2][tid] + sws[3][tid];
    float S2 = sws2[0][tid] + sws2[1][tid] + sws2[2][tid] + sws2[3][tid];
    part[(size_t)tid * PB + blockIdx.x]         = S;
    part[(size_t)(128 + tid) * PB + blockIdx.x] = S2;
  }
}

// ---------------------------------------------------------------- fold per-block partials -> scale/shift
__global__ __launch_bounds__(256) void k_bn_final(const float* __restrict__ part,
    const float* __restrict__ g, const float* __restrict__ b, float* __restrict__ ss) {
  int c = blockIdx.x;   // 128 channels
  int t = threadIdx.x;  // 256
  float s = 0.f, s2 = 0.f;
  for (int i = t; i < GG; i += 256) {
    s  += part[(size_t)c * PB + i];
    s2 += part[(size_t)(128 + c) * PB + i];
  }
  __shared__ float rs[256], rs2[256];
  rs[t] = s; rs2[t] = s2; __syncthreads();
  for (int off = 128; off > 0; off >>= 1) {
    if (t < off) { rs[t] += rs[t + off]; rs2[t] += rs2[t + off]; }
    __syncthreads();
  }
  if (t == 0) {
    float mu = rs[0] / (float)NN;
    float var = rs2[0] / (float)NN - mu * mu;
    float rcp = rsqrtf(var + BN_EPS);
    float sc = rcp * g[c];
    ss[c] = sc;
    ss[128 + c] = b[c] - mu * sc;
  }
}

// ---------------------------------------------------------------- graph mean-pool (raw fp16 sums)
__global__ __launch_bounds__(128) void k_pool(const unsigned short* __restrict__ hb,
    const int* __restrict__ batch, float* __restrict__ pool) {
  int c = threadIdx.x;
  int n0 = blockIdx.x * 256;
  if (n0 >= NN) return;
  int nend = n0 + 256; if (nend > NN) nend = NN;
  int cur = batch[n0];
  float run = 0.f;
  for (int n = n0; n < nend; ++n) {
    int g = batch[n];
    if (g != cur) { atomicAdd(&pool[(size_t)cur * 128 + c], run); run = 0.f; cur = g; }
    run += h2f(hb[(size_t)n * 128 + c]);
  }
  atomicAdd(&pool[(size_t)cur * 128 + c], run);
}

__global__ __launch_bounds__(128) void k_final(const float* __restrict__ pool,
    const int* __restrict__ batch, const float* __restrict__ ss, float* __restrict__ out) {
  int g = blockIdx.x;
  int c = threadIdx.x;
  __shared__ int cnt;
  if (c == 0) {
    int lo = lower_bound_dev(batch, NN, g);
    int hi = lower_bound_dev(batch, NN, g + 1);
    cnt = hi - lo;
  }
  __syncthreads();
  float d = (float)(cnt > 1 ? cnt : 1);
  out[(size_t)g * 128 + c] = fmaf(pool[(size_t)g * 128 + c] / d, ss[c], ss[128 + c]);
}

// ---------------------------------------------------------------- launch
extern "C" void kernel_launch(void* const* d_in, const int* in_sizes, int n_in,
                              void* d_out, int out_size, void* d_ws, size_t ws_size,
                              hipStream_t stream) {
  const float* x     = (const float*)d_in[0];
  const int*   ei    = (const int*)d_in[1];
  const int*   batch = (const int*)d_in[2];
  const float* gg[3] = {(const float*)d_in[6], (const float*)d_in[11], (const float*)d_in[16]};
  const float* bbv[3]= {(const float*)d_in[7], (const float*)d_in[12], (const float*)d_in[17]};
  const int* src = ei;
  const int* dst = ei + NE;

  uintptr_t p = ((uintptr_t)d_ws + 255) & ~(uintptr_t)255;
  auto alloc = [&](size_t bytes) { uintptr_t r = p; p = (p + bytes + 255) & ~(uintptr_t)255; return r; };

  unsigned int* pairs = (unsigned int*)alloc((size_t)NB * BCAP * 4);
  int* gcur  = (int*)alloc(NB * 4);
  int* offs  = (int*)alloc((TOT + 1) * 4);
  int* nbr   = (int*)alloc((size_t)2 * NE * 4);
  unsigned short* xb   = (unsigned short*)alloc((size_t)NN * 64 * 2);
  unsigned short* hb0  = (unsigned short*)alloc((size_t)NN * 128 * 2);
  unsigned short* hb1  = (unsigned short*)alloc((size_t)NN * 128 * 2);
  unsigned short* hb2  = (unsigned short*)alloc((size_t)NN * 128 * 2);
  unsigned short* aggi = (unsigned short*)alloc((size_t)NN * 128 * 2);
  unsigned short* aggo = (unsigned short*)alloc((size_t)NN * 128 * 2);
  unsigned short* wt   = (unsigned short*)alloc(122880 * 2);
  float* part  = (float*)alloc((size_t)256 * PB * 4);
  float* ss_id = (float*)alloc(256 * 4);
  float* ss0   = (float*)alloc(256 * 4);
  float* ss1   = (float*)alloc(256 * 4);
  float* ss2   = (float*)alloc(256 * 4);
  float* pool  = (float*)alloc((size_t)NG * 128 * 4);

  // init: cvt + weight swizzle + ssid + zero gcur/pool (one dispatch)
  WtArgs wa;
  wa.W[0] = (const float*)d_in[3];  wa.W[1] = (const float*)d_in[4];  wa.W[2] = (const float*)d_in[5];
  wa.W[3] = (const float*)d_in[8];  wa.W[4] = (const float*)d_in[9];  wa.W[5] = (const float*)d_in[10];
  wa.W[6] = (const float*)d_in[13]; wa.W[7] = (const float*)d_in[14]; wa.W[8] = (const float*)d_in[15];
  k_init<<<INITB, 256, 0, stream>>>(x, xb, wa, wt, ss_id, gcur, pool);

  // CSR build (bucketed, write-combined, single-pass scatter, self-based p2)
  k_p1<<<P1B, 512, 0, stream>>>(src, dst, gcur, pairs);
  k_p2<<<NB, 256, 0, stream>>>(pairs, gcur, offs, nbr);

  // layer 0 (KD=64): xb -> hb0
  k_gather<64><<<(TOT + 31) / 32, 256, 0, stream>>>(xb, ss_id, offs, nbr, aggi, aggo);
  k_gemm<64><<<GG, 256, 0, stream>>>(xb, ss_id, aggi, aggo, wt + 0, hb0, part);
  k_bn_final<<<128, 256, 0, stream>>>(part, gg[0], bbv[0], ss0);

  // layer 1 (KD=128): hb0 -> hb1
  k_gather<128><<<(TOT + 15) / 16, 256, 0, stream>>>(hb0, ss0, offs, nbr, aggi, aggo);
  k_gemm<128><<<GG, 256, 0, stream>>>(hb0, ss0, aggi, aggo, wt + 24576, hb1, part);
  k_bn_final<<<128, 256, 0, stream>>>(part, gg[1], bbv[1], ss1);

  // layer 2 (KD=128): hb1 -> hb2
  k_gather<128><<<(TOT + 15) / 16, 256, 0, stream>>>(hb1, ss1, offs, nbr, aggi, aggo);
  k_gemm<128><<<GG, 256, 0, stream>>>(hb1, ss1, aggi, aggo, wt + 73728, hb2, part);
  k_bn_final<<<128, 256, 0, stream>>>(part, gg[2], bbv[2], ss2);

  // pool
  k_pool<<<(NN + 255) / 256, 128, 0, stream>>>(hb2, batch, pool);
  k_final<<<NG, 128, 0, stream>>>(pool, batch, ss2, (float*)d_out);
}